// Round 12
// baseline (89.288 us; speedup 1.0000x reference)
//
#include <hip/hip_runtime.h>

#define CH   64
#define NTOT 4096
#define NB   4
#define L2E  1.44269504088896340736f

typedef short  short4v  __attribute__((ext_vector_type(4)));
typedef short  short8v  __attribute__((ext_vector_type(8)));
typedef float  floatx4  __attribute__((ext_vector_type(4)));

static __device__ __forceinline__ unsigned pk2bf(float lo, float hi) {
    unsigned r;
    asm("v_cvt_pk_bf16_f32 %0, %1, %2" : "=v"(r) : "v"(lo), "v"(hi));
    return r;
}
static __device__ __forceinline__ float ex2(float x) {
    return __builtin_amdgcn_exp2f(x);
}
static __device__ __forceinline__ short f2bf(float f) {
    union { float f; unsigned u; } v; v.f = f;
    unsigned r = v.u + 0x7FFFu + ((v.u >> 16) & 1u);
    return (short)(r >> 16);
}
static __device__ __forceinline__ float bf2f(short s) {
    union { unsigned u; float f; } v; v.u = ((unsigned)(unsigned short)s) << 16;
    return v.f;
}

#define MFMA16(A, B, C) __builtin_amdgcn_mfma_f32_16x16x32_bf16(A, B, C, 0, 0, 0)

// ---------------------------------------------------------------------------
// Kernel 1: QKV projection via bf16 hi/lo-split MFMA (fp32-grade precision).
//   kT, qT : (B, N, C) bf16;  v : (B, C, N) bf16
// ---------------------------------------------------------------------------
__global__ __launch_bounds__(256) void qkv_mfma(
    const float* __restrict__ x,
    const float* __restrict__ Wk, const float* __restrict__ Wq,
    const float* __restrict__ Wv,
    short* __restrict__ kT, short* __restrict__ qT, short* __restrict__ vg)
{
    __shared__ __align__(16) short xhi[64 * 72];
    __shared__ __align__(16) short xlo[64 * 72];
    __shared__ __align__(16) short whi[64 * 72];
    __shared__ __align__(16) short wlo[64 * 72];

    const int tid = threadIdx.x;
    const int w = tid >> 6, l = tid & 63, g = l >> 4, ln = l & 15;
    const int b  = blockIdx.x >> 6;
    const int n0 = (blockIdx.x & 63) << 6;
    const float* xb = x + ((size_t)b << 18);

    #pragma unroll
    for (int i = 0; i < 4; ++i) {
        int idx = tid + (i << 8);
        int c = idx >> 4, n4 = (idx & 15) << 2;
        float4 xv = *(const float4*)&xb[c * 4096 + n0 + n4];
        float xa[4] = {xv.x, xv.y, xv.z, xv.w};
        #pragma unroll
        for (int j = 0; j < 4; ++j) {
            short h = f2bf(xa[j]);
            xhi[(n4 + j) * 72 + c] = h;
            xlo[(n4 + j) * 72 + c] = f2bf(xa[j] - bf2f(h));
        }
    }

    const int wo = tid >> 2, wc = (tid & 3) << 4;
    #pragma unroll
    for (int j2 = 0; j2 < 4; ++j2) {
        float4 a = *(const float4*)&Wk[wo * 64 + wc + (j2 << 2)];
        float aa[4] = {a.x, a.y, a.z, a.w};
        #pragma unroll
        for (int j = 0; j < 4; ++j) {
            short h = f2bf(aa[j]);
            whi[wo * 72 + wc + (j2 << 2) + j] = h;
            wlo[wo * 72 + wc + (j2 << 2) + j] = f2bf(aa[j] - bf2f(h));
        }
    }
    __syncthreads();

    short8v xh0 = *(const short8v*)&xhi[((w << 4) + ln) * 72 + (g << 3)];
    short8v xh1 = *(const short8v*)&xhi[((w << 4) + ln) * 72 + 32 + (g << 3)];
    short8v xl0 = *(const short8v*)&xlo[((w << 4) + ln) * 72 + (g << 3)];
    short8v xl1 = *(const short8v*)&xlo[((w << 4) + ln) * 72 + 32 + (g << 3)];

    #pragma unroll
    for (int m = 0; m < 3; ++m) {
        if (m > 0) {
            const float* W = (m == 1) ? Wq : Wv;
            #pragma unroll
            for (int j2 = 0; j2 < 4; ++j2) {
                float4 a = *(const float4*)&W[wo * 64 + wc + (j2 << 2)];
                float aa[4] = {a.x, a.y, a.z, a.w};
                #pragma unroll
                for (int j = 0; j < 4; ++j) {
                    short h = f2bf(aa[j]);
                    whi[wo * 72 + wc + (j2 << 2) + j] = h;
                    wlo[wo * 72 + wc + (j2 << 2) + j] = f2bf(aa[j] - bf2f(h));
                }
            }
            __syncthreads();
        }

        #pragma unroll
        for (int ot = 0; ot < 4; ++ot) {
            short8v ah0 = *(const short8v*)&whi[((ot << 4) + ln) * 72 + (g << 3)];
            short8v ah1 = *(const short8v*)&whi[((ot << 4) + ln) * 72 + 32 + (g << 3)];
            short8v al0 = *(const short8v*)&wlo[((ot << 4) + ln) * 72 + (g << 3)];
            short8v al1 = *(const short8v*)&wlo[((ot << 4) + ln) * 72 + 32 + (g << 3)];
            floatx4 acc = (floatx4){0.f, 0.f, 0.f, 0.f};
            if (m < 2) {
                acc = MFMA16(ah0, xh0, acc);
                acc = MFMA16(ah1, xh1, acc);
                acc = MFMA16(al0, xh0, acc);
                acc = MFMA16(al1, xh1, acc);
                acc = MFMA16(ah0, xl0, acc);
                acc = MFMA16(ah1, xl1, acc);
                short* dst = ((m == 0) ? kT : qT) + ((size_t)b << 18);
                uint2 p;
                p.x = pk2bf(acc[0], acc[1]);
                p.y = pk2bf(acc[2], acc[3]);
                *(uint2*)&dst[(size_t)(n0 + (w << 4) + ln) * 64 + (ot << 4) + (g << 2)] = p;
            } else {
                acc = MFMA16(xh0, ah0, acc);
                acc = MFMA16(xh1, ah1, acc);
                acc = MFMA16(xl0, ah0, acc);
                acc = MFMA16(xl1, ah1, acc);
                acc = MFMA16(xh0, al0, acc);
                acc = MFMA16(xh1, al1, acc);
                short* dst = vg + ((size_t)b << 18);
                uint2 p;
                p.x = pk2bf(acc[0], acc[1]);
                p.y = pk2bf(acc[2], acc[3]);
                *(uint2*)&dst[(size_t)((ot << 4) + ln) * 4096 + n0 + (w << 4) + (g << 2)] = p;
            }
        }
        __syncthreads();
    }
}

// ---------------------------------------------------------------------------
// Kernel 2: barrier-free flash-attention partial.
// grid = 512 (4 kc x 4 b x 32 qblk), 256 threads = 4 INDEPENDENT waves.
// Wave w: 32 queries (rows n0+32w..+31) x 1024-key chunk, 32 tiles of 32 keys.
// K and V fragments read global->reg (L2-resident per XCD); only P uses
// per-wave private LDS (same-wave ds ordering, no __syncthreads anywhere).
// ---------------------------------------------------------------------------
__global__ __launch_bounds__(256) void attn_partial(
    const short* __restrict__ kT, const short* __restrict__ qT,
    const short* __restrict__ vg,
    float* __restrict__ opart, float* __restrict__ mlpart)
{
    __shared__ __align__(16) short smem[4 * 4352];   // 4 x 8704 B per-wave

    const int tid = threadIdx.x;
    const int w = tid >> 6, l = tid & 63, g = l >> 4, ln = l & 15;

    const int bid = blockIdx.x;
    const int xcd = bid & 7, grp = bid >> 3;
    const int bk  = (xcd << 1) | (grp >> 5);
    const int b   = bk >> 2, kc = bk & 3;
    const int qblk = grp & 31;
    const int n0   = qblk << 7;
    const int part = (((b << 2) | kc) << 5) | qblk;
    const int kbase = kc << 10;

    const short* kTb = kT + ((size_t)b << 18);
    const short* qTb = qT + ((size_t)b << 18);
    const short* vb  = vg + ((size_t)b << 18);

    short* const PsW = smem + w * 4352;            // [32 q][40 m] bf16 P
    float* const xp  = (float*)(smem + w * 4352);  // [32 q][68 c] f32 (post-loop)

    // query fragments (rows of kT), loaded once
    const size_t qr0 = (size_t)(n0 + (w << 5) + ln) * 64;
    const size_t qr1 = (size_t)(n0 + (w << 5) + 16 + ln) * 64;
    short8v bS0 = *(const short8v*)&kTb[qr0 + (g << 3)];
    short8v bS1 = *(const short8v*)&kTb[qr0 + 32 + (g << 3)];
    short8v bS2 = *(const short8v*)&kTb[qr1 + (g << 3)];
    short8v bS3 = *(const short8v*)&kTb[qr1 + 32 + (g << 3)];

    float mrun0 = -1e30f, lrun0 = 0.f;
    float mrun1 = -1e30f, lrun1 = 0.f;
    floatx4 acc0[4], acc1[4];
    #pragma unroll
    for (int ct = 0; ct < 4; ++ct) {
        acc0[ct] = (floatx4){0.f, 0.f, 0.f, 0.f};
        acc1[ct] = (floatx4){0.f, 0.f, 0.f, 0.f};
    }

    for (int t = 0; t < 32; ++t) {
        const int m0 = kbase + (t << 5);

        // K fragments (key rows, contiguous 128B rows -> coalesced)
        short8v ka00 = *(const short8v*)&qTb[(size_t)(m0 + ln) * 64 + (g << 3)];
        short8v ka01 = *(const short8v*)&qTb[(size_t)(m0 + ln) * 64 + 32 + (g << 3)];
        short8v ka10 = *(const short8v*)&qTb[(size_t)(m0 + 16 + ln) * 64 + (g << 3)];
        short8v ka11 = *(const short8v*)&qTb[(size_t)(m0 + 16 + ln) * 64 + 32 + (g << 3)];
        // V fragments ((C,N) layout == PV A-fragment layout, direct)
        short8v va0 = *(const short8v*)&vb[(size_t)(ln)      * 4096 + m0 + (g << 3)];
        short8v va1 = *(const short8v*)&vb[(size_t)(16 + ln) * 4096 + m0 + (g << 3)];
        short8v va2 = *(const short8v*)&vb[(size_t)(32 + ln) * 4096 + m0 + (g << 3)];
        short8v va3 = *(const short8v*)&vb[(size_t)(48 + ln) * 4096 + m0 + (g << 3)];

        // ---- S^T tiles: D[m16][q16], two m-subtiles x two query groups ----
        floatx4 s00, s01, s10, s11;
        floatx4 z = (floatx4){0.f, 0.f, 0.f, 0.f};
        __builtin_amdgcn_s_setprio(1);
        s00 = MFMA16(ka00, bS0, z);  s00 = MFMA16(ka01, bS1, s00);
        s01 = MFMA16(ka10, bS0, z);  s01 = MFMA16(ka11, bS1, s01);
        s10 = MFMA16(ka00, bS2, z);  s10 = MFMA16(ka01, bS3, s10);
        s11 = MFMA16(ka10, bS2, z);  s11 = MFMA16(ka11, bS3, s11);
        __builtin_amdgcn_s_setprio(0);

        // ---- online softmax, group 0 (8 in-lane values + 2 shfl) ----
        {
            float mx = fmaxf(fmaxf(fmaxf(s00[0], s00[1]), fmaxf(s00[2], s00[3])),
                             fmaxf(fmaxf(s01[0], s01[1]), fmaxf(s01[2], s01[3])));
            mx = fmaxf(mx, __shfl_xor(mx, 16));
            mx = fmaxf(mx, __shfl_xor(mx, 32));
            if (!__all(mx <= mrun0)) {
                float mnew = fmaxf(mrun0, mx);
                float fs = ex2((mrun0 - mnew) * L2E);
                mrun0 = mnew;
                lrun0 *= fs;
                #pragma unroll
                for (int ct = 0; ct < 4; ++ct) {
                    acc0[ct][0] *= fs; acc0[ct][1] *= fs;
                    acc0[ct][2] *= fs; acc0[ct][3] *= fs;
                }
            }
            const float nm = -mrun0 * L2E;
            float p0 = ex2(__builtin_fmaf(s00[0], L2E, nm));
            float p1 = ex2(__builtin_fmaf(s00[1], L2E, nm));
            float p2 = ex2(__builtin_fmaf(s00[2], L2E, nm));
            float p3 = ex2(__builtin_fmaf(s00[3], L2E, nm));
            float p4 = ex2(__builtin_fmaf(s01[0], L2E, nm));
            float p5 = ex2(__builtin_fmaf(s01[1], L2E, nm));
            float p6 = ex2(__builtin_fmaf(s01[2], L2E, nm));
            float p7 = ex2(__builtin_fmaf(s01[3], L2E, nm));
            uint2 pa, pb;
            pa.x = pk2bf(p0, p1);  pa.y = pk2bf(p2, p3);
            pb.x = pk2bf(p4, p5);  pb.y = pk2bf(p6, p7);
            *(uint2*)&PsW[ln * 40 + (g << 2)]      = pa;
            *(uint2*)&PsW[ln * 40 + 16 + (g << 2)] = pb;
            float s = ((p0 + p1) + (p2 + p3)) + ((p4 + p5) + (p6 + p7));
            s += __shfl_xor(s, 16);
            s += __shfl_xor(s, 32);
            lrun0 += s;
        }
        // ---- online softmax, group 1 ----
        {
            float mx = fmaxf(fmaxf(fmaxf(s10[0], s10[1]), fmaxf(s10[2], s10[3])),
                             fmaxf(fmaxf(s11[0], s11[1]), fmaxf(s11[2], s11[3])));
            mx = fmaxf(mx, __shfl_xor(mx, 16));
            mx = fmaxf(mx, __shfl_xor(mx, 32));
            if (!__all(mx <= mrun1)) {
                float mnew = fmaxf(mrun1, mx);
                float fs = ex2((mrun1 - mnew) * L2E);
                mrun1 = mnew;
                lrun1 *= fs;
                #pragma unroll
                for (int ct = 0; ct < 4; ++ct) {
                    acc1[ct][0] *= fs; acc1[ct][1] *= fs;
                    acc1[ct][2] *= fs; acc1[ct][3] *= fs;
                }
            }
            const float nm = -mrun1 * L2E;
            float p0 = ex2(__builtin_fmaf(s10[0], L2E, nm));
            float p1 = ex2(__builtin_fmaf(s10[1], L2E, nm));
            float p2 = ex2(__builtin_fmaf(s10[2], L2E, nm));
            float p3 = ex2(__builtin_fmaf(s10[3], L2E, nm));
            float p4 = ex2(__builtin_fmaf(s11[0], L2E, nm));
            float p5 = ex2(__builtin_fmaf(s11[1], L2E, nm));
            float p6 = ex2(__builtin_fmaf(s11[2], L2E, nm));
            float p7 = ex2(__builtin_fmaf(s11[3], L2E, nm));
            uint2 pa, pb;
            pa.x = pk2bf(p0, p1);  pa.y = pk2bf(p2, p3);
            pb.x = pk2bf(p4, p5);  pb.y = pk2bf(p6, p7);
            *(uint2*)&PsW[(16 + ln) * 40 + (g << 2)]      = pa;
            *(uint2*)&PsW[(16 + ln) * 40 + 16 + (g << 2)] = pb;
            float s = ((p0 + p1) + (p2 + p3)) + ((p4 + p5) + (p6 + p7));
            s += __shfl_xor(s, 16);
            s += __shfl_xor(s, 32);
            lrun1 += s;
        }

        // ---- PV: K=32, one MFMA per (ct, group); P via per-wave LDS ----
        short8v bp0 = *(const short8v*)&PsW[ln * 40 + (g << 3)];
        short8v bp1 = *(const short8v*)&PsW[(16 + ln) * 40 + (g << 3)];
        __builtin_amdgcn_s_setprio(1);
        acc0[0] = MFMA16(va0, bp0, acc0[0]);  acc1[0] = MFMA16(va0, bp1, acc1[0]);
        acc0[1] = MFMA16(va1, bp0, acc0[1]);  acc1[1] = MFMA16(va1, bp1, acc1[1]);
        acc0[2] = MFMA16(va2, bp0, acc0[2]);  acc1[2] = MFMA16(va2, bp1, acc1[2]);
        acc0[3] = MFMA16(va3, bp0, acc0[3]);  acc1[3] = MFMA16(va3, bp1, acc1[3]);
        __builtin_amdgcn_s_setprio(0);
    }

    // ---- emit: per-wave LDS transpose (overlays P buffer; same wave) ----
    #pragma unroll
    for (int ct = 0; ct < 4; ++ct)
        #pragma unroll
        for (int r = 0; r < 4; ++r) {
            xp[ln * 68 + (ct << 4) + (g << 2) + r]        = acc0[ct][r];
            xp[(16 + ln) * 68 + (ct << 4) + (g << 2) + r] = acc1[ct][r];
        }
    if (g == 0) {
        mlpart[(size_t)part * 256 + (w << 5) + ln]            = mrun0;
        mlpart[(size_t)part * 256 + (w << 5) + 16 + ln]       = mrun1;
        mlpart[(size_t)part * 256 + 128 + (w << 5) + ln]      = lrun0;
        mlpart[(size_t)part * 256 + 128 + (w << 5) + 16 + ln] = lrun1;
    }
    {
        int lq = l >> 1, c0 = (l & 1) << 5;
        float* Ob = opart + (size_t)part * 8192 + (size_t)((w << 5) + lq) * 64 + c0;
        const float* Xp = &xp[lq * 68 + c0];
        #pragma unroll
        for (int j = 0; j < 8; ++j)
            *(float4*)&Ob[j << 2] = *(const float4*)&Xp[j << 2];
    }
}

// ---------------------------------------------------------------------------
// Kernel 3: merge 4 key-chunk partials + W2 + BN + ReLU + residual.
// ---------------------------------------------------------------------------
__global__ __launch_bounds__(256) void attn_merge(
    const float* __restrict__ opart, const float* __restrict__ mlpart,
    const float* __restrict__ W2,
    const float* __restrict__ gamma, const float* __restrict__ beta,
    const float* __restrict__ rmean, const float* __restrict__ rvar,
    const float* __restrict__ x, float* __restrict__ out)
{
    __shared__ __align__(16) short attL[64 * 72];
    __shared__ __align__(16) short w2s [64 * 72];
    __shared__ float wgt[4][64];
    __shared__ float linv[64];

    const int tid = threadIdx.x;
    const int w = tid >> 6, l = tid & 63, g = l >> 4, ln = l & 15;

    const int b      = blockIdx.x >> 6;
    const int qblk64 = blockIdx.x & 63;
    const int n0     = qblk64 << 6;
    const int qb128  = qblk64 >> 1;
    const int qoff   = (qblk64 & 1) << 6;

    if (tid < 64) {
        float mv[4], lv[4];
        #pragma unroll
        for (int kc = 0; kc < 4; ++kc) {
            int part = (((b << 2) | kc) << 5) | qb128;
            mv[kc] = mlpart[(size_t)part * 256 + qoff + tid];
            lv[kc] = mlpart[(size_t)part * 256 + 128 + qoff + tid];
        }
        float mm = fmaxf(fmaxf(mv[0], mv[1]), fmaxf(mv[2], mv[3]));
        float den = 0.f;
        #pragma unroll
        for (int kc = 0; kc < 4; ++kc) {
            float wk = ex2((mv[kc] - mm) * L2E);
            wgt[kc][tid] = wk;
            den += wk * lv[kc];
        }
        linv[tid] = 1.0f / den;
    }
    for (int i = tid; i < 1024; i += 256) {
        int r = i >> 4, c4 = (i & 15) << 2;
        float4 wv = *(const float4*)&W2[(r << 6) + c4];
        uint2 s4;
        s4.x = pk2bf(wv.x, wv.y);
        s4.y = pk2bf(wv.z, wv.w);
        *(uint2*)&w2s[r * 72 + c4] = s4;
    }
    __syncthreads();

    {
        int q = tid >> 2, c16 = (tid & 3) << 4;
        float a[16] = {};
        #pragma unroll
        for (int kc = 0; kc < 4; ++kc) {
            int part = (((b << 2) | kc) << 5) | qb128;
            float wk = wgt[kc][q];
            const float* Ob = opart + (size_t)part * 8192 + (qoff + q) * 64 + c16;
            #pragma unroll
            for (int i = 0; i < 4; ++i) {
                float4 o4 = *(const float4*)&Ob[i << 2];
                a[(i << 2) + 0] += wk * o4.x;
                a[(i << 2) + 1] += wk * o4.y;
                a[(i << 2) + 2] += wk * o4.z;
                a[(i << 2) + 3] += wk * o4.w;
            }
        }
        float li = linv[q];
        #pragma unroll
        for (int i = 0; i < 4; ++i) {
            uint2 s4;
            s4.x = pk2bf(a[(i << 2) + 0] * li, a[(i << 2) + 1] * li);
            s4.y = pk2bf(a[(i << 2) + 2] * li, a[(i << 2) + 3] * li);
            *(uint2*)&attL[q * 72 + c16 + (i << 2)] = s4;
        }
    }
    __syncthreads();

    short8v bA0 = *(const short8v*)&attL[((w << 4) + ln) * 72 + (g << 3)];
    short8v bA1 = *(const short8v*)&attL[((w << 4) + ln) * 72 + 32 + (g << 3)];
    const int nq = n0 + (w << 4) + ln;
    #pragma unroll
    for (int ot = 0; ot < 4; ++ot) {
        short8v a0 = *(const short8v*)&w2s[((ot << 4) + ln) * 72 + (g << 3)];
        short8v a1 = *(const short8v*)&w2s[((ot << 4) + ln) * 72 + 32 + (g << 3)];
        floatx4 acc = (floatx4){0.f, 0.f, 0.f, 0.f};
        acc = MFMA16(a0, bA0, acc);
        acc = MFMA16(a1, bA1, acc);
        int o0 = (ot << 4) + (g << 2);
        float4 gm = *(const float4*)&gamma[o0];
        float4 bt = *(const float4*)&beta [o0];
        float4 rm = *(const float4*)&rmean[o0];
        float4 rv = *(const float4*)&rvar [o0];
        float gma[4] = {gm.x, gm.y, gm.z, gm.w};
        float bta[4] = {bt.x, bt.y, bt.z, bt.w};
        float rma[4] = {rm.x, rm.y, rm.z, rm.w};
        float rva[4] = {rv.x, rv.y, rv.z, rv.w};
        #pragma unroll
        for (int r = 0; r < 4; ++r) {
            float inv  = gma[r] * __frsqrt_rn(rva[r] + 1e-5f);
            float bias = bta[r] - rma[r] * inv;
            size_t ga = (((size_t)(b << 6) + o0 + r) << 12) + nq;
            out[ga] = fmaxf(acc[r] * inv + bias, 0.f) + x[ga];
        }
    }
}

// ---------------------------------------------------------------------------
extern "C" void kernel_launch(void* const* d_in, const int* in_sizes, int n_in,
                              void* d_out, int out_size, void* d_ws, size_t ws_size,
                              hipStream_t stream)
{
    const float* x     = (const float*)d_in[0];
    const float* Wk    = (const float*)d_in[1];
    const float* Wq    = (const float*)d_in[2];
    const float* Wv    = (const float*)d_in[3];
    const float* W2    = (const float*)d_in[4];
    const float* gamma = (const float*)d_in[5];
    const float* beta  = (const float*)d_in[6];
    const float* rmean = (const float*)d_in[7];
    const float* rvar  = (const float*)d_in[8];
    float* out = (float*)d_out;

    const size_t plane = (size_t)NB * NTOT * CH;    // 1M elements
    short* kT = (short*)d_ws;
    short* qT = kT + plane;
    short* vv = qT + plane;
    float* opart  = (float*)(vv + plane);           // 512 x 8192 f32 = 16 MB
    float* mlpart = opart + (size_t)512 * 8192;     // 512 x 256  f32 = 0.5 MB

    qkv_mfma    <<<dim3(256), dim3(256), 0, stream>>>(x, Wk, Wq, Wv, kT, qT, vv);
    attn_partial<<<dim3(512), dim3(256), 0, stream>>>(kT, qT, vv, opart, mlpart);
    attn_merge  <<<dim3(256), dim3(256), 0, stream>>>(opart, mlpart, W2, gamma, beta,
                                                      rmean, rvar, x, out);
}